// Round 1
// baseline (186.979 us; speedup 1.0000x reference)
//
#include <hip/hip_runtime.h>
#include <cfloat>

#define NN   1024
#define NE   16384
#define D0   128
#define EDIM 16
#define NH1  64
#define NOUT 40
#define KTOP 8
#define NEGINF (-1000000000.0f)

// ---- workspace layout (bytes) ----
#define OFF_IDMAX   0u            // 1024*1024*4 = 4 MB  (int, last-edge-wins)
#define OFF_IDMIN   4194304u      // 4 MB (unsigned, first-edge-wins)
#define OFF_MX1     8388608u      // 1024*128*4
#define OFF_DEN1    8912896u
#define OFF_NUM1    9437184u
#define OFF_MX2     9961472u      // 1024*64*4
#define OFF_DEN2    10223616u
#define OFF_NUM2    10485760u
#define ZERO_LEN    2359296u      // MX1..NUM2
#define OFF_A       10747904u     // 1024 f
#define OFF_B       10752000u     // 1024 f
#define OFF_DST     10756096u     // 8192 int
#define OFF_EM      10788864u     // 8192 int
#define OFF_M1      10821632u     // 8192*128 f = 4 MB
#define OFF_OUT1    15015936u     // 1024*128 f
#define OFF_T1      15540224u     // 1024*256 f
#define OFF_H       16588800u     // 1024*64 f
#define OFF_M2      16850944u     // 8192*64 f = 2 MB
#define OFF_OUT2    18948096u     // 1024*64 f
#define OFF_T2      19210240u     // 1024*128 f
// total ~19.7 MB

// Scatter original edges into per-(src,dst) cell: max edge id (s_edge last-wins)
// and min edge id (argmax(eq) first-match).
__global__ __launch_bounds__(256) void scatter_kernel(
    const int* __restrict__ ei, int* __restrict__ idmax, unsigned* __restrict__ idmin)
{
    int e = blockIdx.x * 256 + threadIdx.x;
    if (e >= NE) return;
    int s = ei[e];
    int d = ei[NE + e];
    int idx = s * NN + d;
    atomicMax(idmax + idx, e);
    atomicMin(idmin + idx, (unsigned)e);
}

// a[i] = x[i]@w_node, b[i] = x[i]@w_nb
__global__ __launch_bounds__(256) void ab_kernel(
    const float* __restrict__ x, const float* __restrict__ mlp_w,
    float* __restrict__ a, float* __restrict__ b)
{
    int i = blockIdx.x * 256 + threadIdx.x;
    if (i >= NN) return;
    const float* xr = x + i * D0;
    float sa = 0.f, sb = 0.f;
    for (int d = 0; d < D0; d++) {
        float xv = xr[d];
        sa += xv * mlp_w[d];
        sb += xv * mlp_w[D0 + d];
    }
    a[i] = sa;
    b[i] = sb;
}

// Per row i: masked softmax z over edges, v = z + gumbel(u), top-8 (stable),
// plus first-match original-edge lookup for each selected (i,j).
__global__ __launch_bounds__(256) void row_topk_kernel(
    const int* __restrict__ idmax, const unsigned* __restrict__ idmin,
    const float* __restrict__ ea, const float* __restrict__ mlp_w,
    const float* __restrict__ mlp_b, const float* __restrict__ a,
    const float* __restrict__ b, const float* __restrict__ u,
    int* __restrict__ dsti, int* __restrict__ ematch)
{
    __shared__ float sv[NN];
    __shared__ float red_v[256];
    __shared__ int   red_j[256];
    const int i = blockIdx.x;
    const int t = threadIdx.x;
    const int rowoff = i * NN;
    const float bias = mlp_b[0];
    const float ai = a[i];
    float we[EDIM];
    #pragma unroll
    for (int k = 0; k < EDIM; k++) we[k] = mlp_w[2 * D0 + k];

    // scores
    float lmax = NEGINF;
    for (int j = t; j < NN; j += 256) {
        int id = idmax[rowoff + j];
        float s;
        if (id >= 0) {
            const float* er = ea + id * EDIM;
            float se = 0.f;
            #pragma unroll
            for (int k = 0; k < EDIM; k++) se += er[k] * we[k];
            s = ((ai + b[j]) + se) + bias;
        } else {
            s = NEGINF;
        }
        sv[j] = s;
        lmax = fmaxf(lmax, s);
    }
    red_v[t] = lmax;
    __syncthreads();
    for (int stp = 128; stp > 0; stp >>= 1) {
        if (t < stp) red_v[t] = fmaxf(red_v[t], red_v[t + stp]);
        __syncthreads();
    }
    float rowmax = red_v[0];
    __syncthreads();
    bool noedge = (rowmax == NEGINF);

    // exp + sum
    float lsum = 0.f;
    for (int j = t; j < NN; j += 256) {
        float e;
        if (noedge) e = 1.0f;
        else {
            float s = sv[j];
            e = (s == NEGINF) ? 0.0f : expf(s - rowmax);
        }
        sv[j] = e;
        lsum += e;
    }
    __syncthreads();
    red_v[t] = lsum;
    __syncthreads();
    for (int stp = 128; stp > 0; stp >>= 1) {
        if (t < stp) red_v[t] += red_v[t + stp];
        __syncthreads();
    }
    float rsum = red_v[0];
    __syncthreads();

    // v = z + gumbel
    for (int j = t; j < NN; j += 256) {
        float z = sv[j] / rsum;
        float uu = u[rowoff + j];
        float g = -logf(-logf(uu + 1e-20f) + 1e-20f);
        sv[j] = z + g;
    }
    __syncthreads();

    // iterative top-8: (max value, min index)
    for (int sel = 0; sel < KTOP; sel++) {
        float bv = -FLT_MAX;
        int bj = NN;
        for (int j = t; j < NN; j += 256) {
            float v = sv[j];
            if (v > bv || (v == bv && j < bj)) { bv = v; bj = j; }
        }
        red_v[t] = bv; red_j[t] = bj;
        __syncthreads();
        for (int stp = 128; stp > 0; stp >>= 1) {
            if (t < stp) {
                float ov = red_v[t + stp]; int oj = red_j[t + stp];
                if (ov > red_v[t] || (ov == red_v[t] && oj < red_j[t])) {
                    red_v[t] = ov; red_j[t] = oj;
                }
            }
            __syncthreads();
        }
        if (t == 0) {
            int j = red_j[0];
            dsti[i * KTOP + sel] = j;
            unsigned em = idmin[rowoff + j];
            ematch[i * KTOP + sel] = (em == 0xFFFFFFFFu) ? 0 : (int)em;
            sv[j] = -FLT_MAX;   // exclude from next pass
        }
        __syncthreads();
    }
}

// m[n,d] = relu(xin[src(n),d] + (edge_attr[e]@We)[d] + be[d]) + 1e-7 ; atomicMax into mx[dst]
template<int Dd>
__global__ __launch_bounds__(256) void genconv_m_kernel(
    const float* __restrict__ xin, const float* __restrict__ ea,
    const float* __restrict__ we, const float* __restrict__ be,
    const int* __restrict__ ematch, const int* __restrict__ dsti,
    float* __restrict__ m, float* __restrict__ mx)
{
    int gid = blockIdx.x * 256 + threadIdx.x;
    int n = gid / Dd;
    int d = gid % Dd;
    int i = n >> 3;              // src = repeat(arange(N), 8)
    int e = ematch[n];
    const float* er = ea + e * EDIM;
    float ep = 0.f;
    #pragma unroll
    for (int k = 0; k < EDIM; k++) ep += er[k] * we[k * Dd + d];
    ep += be[d];
    float v = xin[i * Dd + d] + ep;
    float mm = fmaxf(v, 0.f) + 1e-7f;
    m[n * Dd + d] = mm;
    int dst = dsti[n];
    atomicMax((int*)(mx + dst * Dd + d), __float_as_int(mm));  // mm>0: int order == float order
}

template<int Dd>
__global__ __launch_bounds__(256) void genconv_w_kernel(
    const float* __restrict__ m, const float* __restrict__ mx,
    const int* __restrict__ dsti, float* __restrict__ den, float* __restrict__ num)
{
    int gid = blockIdx.x * 256 + threadIdx.x;
    int n = gid / Dd;
    int d = gid % Dd;
    int dst = dsti[n];
    float mm = m[n * Dd + d];
    float w = expf(mm - mx[dst * Dd + d]);
    atomicAdd(den + dst * Dd + d, w);
    atomicAdd(num + dst * Dd + d, w * mm);
}

template<int Dd>
__global__ __launch_bounds__(256) void genconv_agg_kernel(
    const float* __restrict__ num, const float* __restrict__ den,
    const float* __restrict__ xin, float* __restrict__ out)
{
    int gid = blockIdx.x * 256 + threadIdx.x;
    float dn = den[gid];
    float agg = num[gid] / (dn > 0.f ? dn : 1.f);
    out[gid] = agg + xin[gid];
}

// C[r,:] = act(A[r,:] @ W + bias); one block per row, Dout threads.
template<int Din, int Dout, bool RELU>
__global__ __launch_bounds__(Dout) void mlp_kernel(
    const float* __restrict__ A, const float* __restrict__ W,
    const float* __restrict__ bias, float* __restrict__ C)
{
    __shared__ float arow[Din];
    int r = blockIdx.x, t = threadIdx.x;
    for (int d = t; d < Din; d += Dout) arow[d] = A[r * Din + d];
    __syncthreads();
    float acc = 0.f;
    for (int d = 0; d < Din; d++) acc += arow[d] * W[d * Dout + t];
    acc += bias[t];
    if (RELU) acc = fmaxf(acc, 0.f);
    C[r * Dout + t] = acc;
}

// h2 = relu(t2 @ c2_w2 + c2_b2); out = mask ? h2 @ fc_w + fc_b : 0
__global__ __launch_bounds__(64) void final_kernel(
    const float* __restrict__ t2, const float* __restrict__ w2,
    const float* __restrict__ b2, const float* __restrict__ fcw,
    const float* __restrict__ fcb, const int* __restrict__ mask,
    float* __restrict__ out)
{
    __shared__ float arow[2 * NH1];
    __shared__ float h2[NH1];
    int r = blockIdx.x, t = threadIdx.x;
    for (int d = t; d < 2 * NH1; d += 64) arow[d] = t2[r * 2 * NH1 + d];
    __syncthreads();
    float acc = 0.f;
    for (int d = 0; d < 2 * NH1; d++) acc += arow[d] * w2[d * NH1 + t];
    acc += b2[t];
    h2[t] = fmaxf(acc, 0.f);
    __syncthreads();
    if (t < NOUT) {
        float o = 0.f;
        for (int d = 0; d < NH1; d++) o += h2[d] * fcw[d * NOUT + t];
        o += fcb[t];
        out[r * NOUT + t] = (mask[r] != 0) ? o : 0.f;
    }
}

extern "C" void kernel_launch(void* const* d_in, const int* in_sizes, int n_in,
                              void* d_out, int out_size, void* d_ws, size_t ws_size,
                              hipStream_t stream) {
    const float* x      = (const float*)d_in[0];
    const float* ea     = (const float*)d_in[1];
    const float* u      = (const float*)d_in[2];
    const float* mlp_w  = (const float*)d_in[3];
    const float* mlp_b  = (const float*)d_in[4];
    const float* c1_we  = (const float*)d_in[5];
    const float* c1_be  = (const float*)d_in[6];
    const float* c1_w1  = (const float*)d_in[7];
    const float* c1_b1  = (const float*)d_in[8];
    const float* c1_w2  = (const float*)d_in[9];
    const float* c1_b2  = (const float*)d_in[10];
    const float* c2_we  = (const float*)d_in[11];
    const float* c2_be  = (const float*)d_in[12];
    const float* c2_w1  = (const float*)d_in[13];
    const float* c2_b1  = (const float*)d_in[14];
    const float* c2_w2  = (const float*)d_in[15];
    const float* c2_b2  = (const float*)d_in[16];
    const float* fc_w   = (const float*)d_in[17];
    const float* fc_b   = (const float*)d_in[18];
    const int*   ei     = (const int*)d_in[20];
    const int*   mask   = (const int*)d_in[21];

    char* ws = (char*)d_ws;
    int*      idmax = (int*)(ws + OFF_IDMAX);
    unsigned* idmin = (unsigned*)(ws + OFF_IDMIN);
    float* mx1  = (float*)(ws + OFF_MX1);
    float* den1 = (float*)(ws + OFF_DEN1);
    float* num1 = (float*)(ws + OFF_NUM1);
    float* mx2  = (float*)(ws + OFF_MX2);
    float* den2 = (float*)(ws + OFF_DEN2);
    float* num2 = (float*)(ws + OFF_NUM2);
    float* a    = (float*)(ws + OFF_A);
    float* b    = (float*)(ws + OFF_B);
    int*   dsti = (int*)(ws + OFF_DST);
    int*   em   = (int*)(ws + OFF_EM);
    float* m1   = (float*)(ws + OFF_M1);
    float* out1 = (float*)(ws + OFF_OUT1);
    float* t1   = (float*)(ws + OFF_T1);
    float* h    = (float*)(ws + OFF_H);
    float* m2   = (float*)(ws + OFF_M2);
    float* out2 = (float*)(ws + OFF_OUT2);
    float* t2   = (float*)(ws + OFF_T2);
    float* out  = (float*)d_out;

    // init: idmax=-1 / idmin=UINT_MAX via 0xFF; accumulators to zero
    hipMemsetAsync(ws + OFF_IDMAX, 0xFF, 2u * 4194304u, stream);
    hipMemsetAsync(ws + OFF_MX1, 0, ZERO_LEN, stream);

    scatter_kernel<<<(NE + 255) / 256, 256, 0, stream>>>(ei, idmax, idmin);
    ab_kernel<<<(NN + 255) / 256, 256, 0, stream>>>(x, mlp_w, a, b);
    row_topk_kernel<<<NN, 256, 0, stream>>>(idmax, idmin, ea, mlp_w, mlp_b, a, b, u, dsti, em);

    // GENConv 1 (D=128)
    genconv_m_kernel<D0><<<(NN * KTOP * D0) / 256, 256, 0, stream>>>(x, ea, c1_we, c1_be, em, dsti, m1, mx1);
    genconv_w_kernel<D0><<<(NN * KTOP * D0) / 256, 256, 0, stream>>>(m1, mx1, dsti, den1, num1);
    genconv_agg_kernel<D0><<<(NN * D0) / 256, 256, 0, stream>>>(num1, den1, x, out1);
    mlp_kernel<128, 256, true><<<NN, 256, 0, stream>>>(out1, c1_w1, c1_b1, t1);
    mlp_kernel<256, 64, true><<<NN, 64, 0, stream>>>(t1, c1_w2, c1_b2, h);  // fused outer relu

    // GENConv 2 (D=64)
    genconv_m_kernel<NH1><<<(NN * KTOP * NH1) / 256, 256, 0, stream>>>(h, ea, c2_we, c2_be, em, dsti, m2, mx2);
    genconv_w_kernel<NH1><<<(NN * KTOP * NH1) / 256, 256, 0, stream>>>(m2, mx2, dsti, den2, num2);
    genconv_agg_kernel<NH1><<<(NN * NH1) / 256, 256, 0, stream>>>(num2, den2, h, out2);
    mlp_kernel<64, 128, true><<<NN, 128, 0, stream>>>(out2, c2_w1, c2_b1, t2);

    final_kernel<<<NN, 64, 0, stream>>>(t2, c2_w2, c2_b2, fc_w, fc_b, mask, out);
}